// Round 1
// baseline (700.051 us; speedup 1.0000x reference)
//
#include <hip/hip_runtime.h>
#include <hip/hip_bf16.h>
#include <math.h>

// Problem: align = einsum('bsh,bh->bs', enc, states)/512; w = softmax(align, axis=1);
//          ctx = einsum('bsh,bs->bh', enc, w). B=32, S=8192, H=512, fp32.
// enc = 512 MiB > L3 --> single fused pass over enc (flash-style online softmax),
// partials combined in a tiny second kernel.

#define BB 32
#define SS 8192
#define HH 512
#define NB 32              // blocks per batch
#define WPB 4              // waves per block
#define NP (NB * WPB)      // partials per batch = 128
#define RPW (SS / NP)      // rows per wave = 64

__global__ __launch_bounds__(256, 4) void attn_pass1(
    const float* __restrict__ states, const float* __restrict__ enc,
    float* __restrict__ align, float* __restrict__ pm,
    float* __restrict__ pl, float* __restrict__ pC)
{
    const int b     = blockIdx.x >> 5;       // / NB
    const int chunk = blockIdx.x & (NB - 1);
    const int lane  = threadIdx.x & 63;
    const int wv    = threadIdx.x >> 6;
    const int p     = chunk * WPB + wv;      // partial index within batch, 0..127

    // states_h fragment: lane l owns h in [4l,4l+4) and [256+4l, 260+4l)
    const float4* st = (const float4*)(states + (size_t)b * HH);
    const float4 sh0 = st[lane];
    const float4 sh1 = st[lane + 64];

    const float* rowbase = enc + ((size_t)b * SS + (size_t)p * RPW) * HH;

    float  m = -1e30f, l = 0.0f;
    float4 c0 = make_float4(0.f, 0.f, 0.f, 0.f);
    float4 c1 = make_float4(0.f, 0.f, 0.f, 0.f);
    float  my_a = 0.0f;                      // lane r keeps align of local row r

    #pragma unroll 4
    for (int r = 0; r < RPW; ++r) {
        const float4* rp = (const float4*)(rowbase + (size_t)r * HH);
        float4 e0 = rp[lane];
        float4 e1 = rp[lane + 64];

        float d = e0.x*sh0.x + e0.y*sh0.y + e0.z*sh0.z + e0.w*sh0.w
                + e1.x*sh1.x + e1.y*sh1.y + e1.z*sh1.z + e1.w*sh1.w;
        #pragma unroll
        for (int off = 1; off < 64; off <<= 1)
            d += __shfl_xor(d, off, 64);

        float a = d * (1.0f / 512.0f);
        my_a = (r == lane) ? a : my_a;

        float mn    = fmaxf(m, a);
        float scale = __expf(m - mn);        // ==1 except when max moves
        float pr    = __expf(a - mn);
        l = fmaf(l, scale, pr);
        c0.x = fmaf(pr, e0.x, c0.x * scale);
        c0.y = fmaf(pr, e0.y, c0.y * scale);
        c0.z = fmaf(pr, e0.z, c0.z * scale);
        c0.w = fmaf(pr, e0.w, c0.w * scale);
        c1.x = fmaf(pr, e1.x, c1.x * scale);
        c1.y = fmaf(pr, e1.y, c1.y * scale);
        c1.z = fmaf(pr, e1.z, c1.z * scale);
        c1.w = fmaf(pr, e1.w, c1.w * scale);
        m = mn;
    }

    align[(size_t)b * SS + (size_t)p * RPW + lane] = my_a;
    if (lane == 0) {
        pm[b * NP + p] = m;
        pl[b * NP + p] = l;
    }
    float4* Cp = (float4*)(pC + (size_t)(b * NP + p) * HH);
    Cp[lane]      = c0;
    Cp[lane + 64] = c1;
}

__global__ __launch_bounds__(256) void attn_pass2(
    const float* __restrict__ align, const float* __restrict__ pm,
    const float* __restrict__ pl, const float* __restrict__ pC,
    float* __restrict__ out_ctx, float* __restrict__ out_w)
{
    const int b = blockIdx.x;
    const int t = threadIdx.x;

    __shared__ float red[NP];
    __shared__ float s_w[NP];
    __shared__ float s_M, s_invL;

    if (t < NP) red[t] = pm[b * NP + t];
    __syncthreads();
    if (t == 0) {
        float M = -1e30f;
        for (int i = 0; i < NP; ++i) M = fmaxf(M, red[i]);
        s_M = M;
    }
    __syncthreads();
    const float M = s_M;
    if (t < NP) s_w[t] = __expf(red[t] - M);
    __syncthreads();
    if (t == 0) {
        float L = 0.0f;
        for (int i = 0; i < NP; ++i) L += s_w[i] * pl[b * NP + i];
        s_invL = 1.0f / L;
    }
    __syncthreads();
    const float invL = s_invL;

    // combine context partials: thread t handles h = t and h = t+256
    float acc0 = 0.0f, acc1 = 0.0f;
    const float* Cb = pC + (size_t)b * NP * HH;
    #pragma unroll 4
    for (int p = 0; p < NP; ++p) {
        float w = s_w[p];
        acc0 = fmaf(w, Cb[(size_t)p * HH + t], acc0);
        acc1 = fmaf(w, Cb[(size_t)p * HH + t + 256], acc1);
    }
    out_ctx[b * HH + t]       = acc0 * invL;
    out_ctx[b * HH + t + 256] = acc1 * invL;

    // weights from stored align
    const float* al = align + (size_t)b * SS;
    float*       ow = out_w + (size_t)b * SS;
    for (int s = t; s < SS; s += 256)
        ow[s] = __expf(al[s] - M) * invL;
}

extern "C" void kernel_launch(void* const* d_in, const int* in_sizes, int n_in,
                              void* d_out, int out_size, void* d_ws, size_t ws_size,
                              hipStream_t stream) {
    const float* states = (const float*)d_in[0];   // (32, 512)
    const float* enc    = (const float*)d_in[1];   // (32, 8192, 512)

    float* out_ctx = (float*)d_out;                    // 32*512 = 16384
    float* out_w   = (float*)d_out + (size_t)BB * HH;  // 32*8192 = 262144

    // workspace layout (floats): align[B*S] | pm[B*NP] | pl[B*NP] | pC[B*NP*H]
    float* ws_align = (float*)d_ws;
    float* ws_pm    = ws_align + (size_t)BB * SS;
    float* ws_pl    = ws_pm    + (size_t)BB * NP;
    float* ws_pC    = ws_pl    + (size_t)BB * NP;
    // total = 262144 + 4096 + 4096 + 2097152 floats ~= 9.5 MB

    attn_pass1<<<BB * NB, 256, 0, stream>>>(states, enc, ws_align, ws_pm, ws_pl, ws_pC);
    attn_pass2<<<BB, 256, 0, stream>>>(ws_align, ws_pm, ws_pl, ws_pC, out_ctx, out_w);
}